// Round 5
// baseline (142.540 us; speedup 1.0000x reference)
//
#include <hip/hip_runtime.h>
#include <hip/hip_bf16.h>

#define N_ROWS 131072
#define K_MIX  256
#define D_DIM  128
#define LDSB_STRIDE 136            // shorts per B row: 128 + 8 pad (rows 272 B, 16B aligned)
#define B_CHUNKS (K_MIX * LDSB_STRIDE / 8)   // 4352 bf16x8 chunks = 69632 B
#define LOG2E 1.4426950408889634f
#define LN2   0.6931471805599453f

typedef float  f32x4  __attribute__((ext_vector_type(4)));
typedef short  bf16x8 __attribute__((ext_vector_type(8)));

__device__ inline bf16x8 pack8(float4 a, float4 b) {
    union { bf16x8 v; __hip_bfloat162 h[4]; } u;
    u.h[0] = __float22bfloat162_rn(make_float2(a.x, a.y));
    u.h[1] = __float22bfloat162_rn(make_float2(a.z, a.w));
    u.h[2] = __float22bfloat162_rn(make_float2(b.x, b.y));
    u.h[3] = __float22bfloat162_rn(make_float2(b.z, b.w));
    return u.v;
}

// -------- prep: ws <- padded bf16(log2e*prec*mu), fp32 0.5*log2e*musq --------
__global__ void prep_kernel(const float* __restrict__ mu,
                            const float* __restrict__ prec,
                            unsigned short* __restrict__ Bp,
                            float* __restrict__ musq)
{
    int idx = blockIdx.x * 256 + threadIdx.x;   // 0..8191 float4s of mu
    int row = idx >> 5;                          // mixture component k
    int c4  = idx & 31;                          // float4 within row
    float4 mv = ((const float4*)mu)[idx];
    float4 pv = ((const float4*)prec)[c4];
    float px = mv.x * pv.x, py = mv.y * pv.y, pz = mv.z * pv.z, pw = mv.w * pv.w;
    union { ushort4 u4; __hip_bfloat162 h[2]; } h;
    h.h[0] = __float22bfloat162_rn(make_float2(px * LOG2E, py * LOG2E));
    h.h[1] = __float22bfloat162_rn(make_float2(pz * LOG2E, pw * LOG2E));
    *(ushort4*)&Bp[row * LDSB_STRIDE + c4 * 4] = h.u4;
    if (c4 == 31) {     // zero the 8-short pad
        bf16x8 z = (bf16x8)0;
        *(bf16x8*)&Bp[row * LDSB_STRIDE + 128] = z;
    }
    float ps = px * mv.x + py * mv.y + pz * mv.z + pw * mv.w;
    ps += __shfl_xor(ps, 1);  ps += __shfl_xor(ps, 2);
    ps += __shfl_xor(ps, 4);  ps += __shfl_xor(ps, 8);
    ps += __shfl_xor(ps, 16);
    if ((threadIdx.x & 31) == 0) musq[row] = 0.5f * LOG2E * ps;
}

// -------- per-rowgroup: MFMA over 2 column halves + online LSE (log2 domain) --------
__device__ inline float do_rowgroup(const bf16x8* a0, const bf16x8* a1,
                                    const unsigned short* sB, const float* sMusq,
                                    int low4, int q)
{
    float m_run[2][4], s_run[2][4];

    #pragma unroll 1
    for (int h = 0; h < 2; ++h) {
        f32x4 acc[2][8];
        #pragma unroll
        for (int c = 0; c < 8; ++c) {
            float mneg = sMusq[(h * 8 + c) * 16 + low4];   // = -0.5*log2e*musq[col]
            #pragma unroll
            for (int i = 0; i < 4; ++i) { acc[0][c][i] = mneg; acc[1][c][i] = mneg; }
        }

        #pragma unroll
        for (int k = 0; k < 4; ++k) {
            #pragma unroll
            for (int c = 0; c < 8; ++c) {
                const unsigned short* bp =
                    &sB[((h * 8 + c) * 16 + low4) * LDSB_STRIDE + k * 32 + q * 8];
                bf16x8 b = *(const bf16x8*)bp;   // ds_read_b128
                acc[0][c] = __builtin_amdgcn_mfma_f32_16x16x32_bf16(a0[k], b, acc[0][c], 0, 0, 0);
                acc[1][c] = __builtin_amdgcn_mfma_f32_16x16x32_bf16(a1[k], b, acc[1][c], 0, 0, 0);
            }
        }

        #pragma unroll
        for (int m = 0; m < 2; ++m) {
            #pragma unroll
            for (int i = 0; i < 4; ++i) {
                float v0 = acc[m][0][i], v1 = acc[m][1][i];
                float v2 = acc[m][2][i], v3 = acc[m][3][i];
                float v4 = acc[m][4][i], v5 = acc[m][5][i];
                float v6 = acc[m][6][i], v7 = acc[m][7][i];
                float hmax = fmaxf(fmaxf(fmaxf(v0, v1), fmaxf(v2, v3)),
                                   fmaxf(fmaxf(v4, v5), fmaxf(v6, v7)));
                float hsum = __builtin_amdgcn_exp2f(v0 - hmax) + __builtin_amdgcn_exp2f(v1 - hmax)
                           + __builtin_amdgcn_exp2f(v2 - hmax) + __builtin_amdgcn_exp2f(v3 - hmax)
                           + __builtin_amdgcn_exp2f(v4 - hmax) + __builtin_amdgcn_exp2f(v5 - hmax)
                           + __builtin_amdgcn_exp2f(v6 - hmax) + __builtin_amdgcn_exp2f(v7 - hmax);
                if (h == 0) {
                    m_run[m][i] = hmax; s_run[m][i] = hsum;
                } else {
                    float mr = m_run[m][i];
                    float mn = fmaxf(mr, hmax);
                    s_run[m][i] = s_run[m][i] * __builtin_amdgcn_exp2f(mr - mn)
                                + hsum        * __builtin_amdgcn_exp2f(hmax - mn);
                    m_run[m][i] = mn;
                }
            }
        }
    }

    // merge (m,s) across the 16 col-lanes; lanes with low4==0 return the lse sum
    float lsum = 0.f;
    #pragma unroll
    for (int m = 0; m < 2; ++m) {
        #pragma unroll
        for (int i = 0; i < 4; ++i) {
            float mr = m_run[m][i], sr = s_run[m][i];
            #pragma unroll
            for (int step = 1; step <= 8; step <<= 1) {
                float mo = __shfl_xor(mr, step);
                float so = __shfl_xor(sr, step);
                float mn = fmaxf(mr, mo);
                sr = sr * __builtin_amdgcn_exp2f(mr - mn)
                   + so * __builtin_amdgcn_exp2f(mo - mn);
                mr = mn;
            }
            if (low4 == 0) lsum += LN2 * (mr + __builtin_amdgcn_logf(sr));
        }
    }
    return lsum;
}

// ---------------- main ----------------
__global__ __launch_bounds__(256, 2)
void mixture_main(const float* __restrict__ x,
                  const unsigned short* __restrict__ Bp,
                  const float* __restrict__ musqg,
                  const float* __restrict__ prec,
                  float* __restrict__ out)
{
    __shared__ __align__(16) unsigned short sB[K_MIX * LDSB_STRIDE];
    __shared__ float sMusq[K_MIX];      // holds -0.5*log2e*musq (acc-init ready)
    __shared__ float sPrec[D_DIM];
    __shared__ float sRed[4];

    const int tid  = threadIdx.x;
    const int lane = tid & 63;
    const int wave = tid >> 6;
    const int low4 = lane & 15;
    const int q    = lane >> 4;

    const float4* x4 = (const float4*)x;
    const int rbase = blockIdx.x * 256 + wave * 32;
    const float4* p0g0 = x4 + (size_t)(rbase + low4) * 32;
    const float4* p1g0 = p0g0 + 16 * 32;
    const float4* p0g1 = p0g0 + 128 * 32;
    const float4* p1g1 = p1g0 + 128 * 32;

    // ---- issue rg0 x loads first (overlap with B staging) ----
    float4 xv[4][4];
    #pragma unroll
    for (int k = 0; k < 4; ++k) {
        const int d4 = k * 8 + q * 2;
        xv[k][0] = p0g0[d4]; xv[k][1] = p0g0[d4 + 1];
        xv[k][2] = p1g0[d4]; xv[k][3] = p1g0[d4 + 1];
    }

    // ---- stage B via async global->LDS DMA (lane-contiguous layout) ----
    {
        #pragma unroll
        for (int i = 0; i < B_CHUNKS / 256; ++i) {   // 17 iterations
            const int chunk = i * 256 + wave * 64;   // wave-uniform chunk base
            const unsigned short* g = Bp + (size_t)(chunk + lane) * 8;
            unsigned short* l = sB + (size_t)(chunk + lane) * 8;
            __builtin_amdgcn_global_load_lds(
                (const __attribute__((address_space(1))) unsigned int*)g,
                (__attribute__((address_space(3))) unsigned int*)l,
                16, 0, 0);
        }
        sMusq[tid] = -musqg[tid];
        if (tid < D_DIM) sPrec[tid] = prec[tid];
    }
    __syncthreads();

    float lacc = 0.f;    // per-lane partial of (0.5*xsq - lse)

    // ---- rg0 pack + xsq (xv dies here) ----
    float xsA = 0.f, xsB = 0.f;
    bf16x8 a0[4], a1[4];
    #pragma unroll
    for (int k = 0; k < 4; ++k) {
        const int d4 = k * 8 + q * 2;
        float4 pa = *(const float4*)&sPrec[d4 * 4];
        float4 pb = *(const float4*)&sPrec[d4 * 4 + 4];
        xsA += pa.x*xv[k][0].x*xv[k][0].x + pa.y*xv[k][0].y*xv[k][0].y
             + pa.z*xv[k][0].z*xv[k][0].z + pa.w*xv[k][0].w*xv[k][0].w;
        xsB += pb.x*xv[k][1].x*xv[k][1].x + pb.y*xv[k][1].y*xv[k][1].y
             + pb.z*xv[k][1].z*xv[k][1].z + pb.w*xv[k][1].w*xv[k][1].w;
        xsA += pa.x*xv[k][2].x*xv[k][2].x + pa.y*xv[k][2].y*xv[k][2].y
             + pa.z*xv[k][2].z*xv[k][2].z + pa.w*xv[k][2].w*xv[k][2].w;
        xsB += pb.x*xv[k][3].x*xv[k][3].x + pb.y*xv[k][3].y*xv[k][3].y
             + pb.z*xv[k][3].z*xv[k][3].z + pb.w*xv[k][3].w*xv[k][3].w;
        a0[k] = pack8(xv[k][0], xv[k][1]);
        a1[k] = pack8(xv[k][2], xv[k][3]);
    }
    lacc += 0.5f * (xsA + xsB);

    // ---- prefetch rg1's x NOW — in flight during rg0's MFMA + LSE ----
    float4 xw[4][4];
    #pragma unroll
    for (int k = 0; k < 4; ++k) {
        const int d4 = k * 8 + q * 2;
        xw[k][0] = p0g1[d4]; xw[k][1] = p0g1[d4 + 1];
        xw[k][2] = p1g1[d4]; xw[k][3] = p1g1[d4 + 1];
    }

    // ---- rg0 compute ----
    lacc -= do_rowgroup(a0, a1, sB, sMusq, low4, q);

    // ---- rg1 pack + xsq ----
    xsA = 0.f; xsB = 0.f;
    #pragma unroll
    for (int k = 0; k < 4; ++k) {
        const int d4 = k * 8 + q * 2;
        float4 pa = *(const float4*)&sPrec[d4 * 4];
        float4 pb = *(const float4*)&sPrec[d4 * 4 + 4];
        xsA += pa.x*xw[k][0].x*xw[k][0].x + pa.y*xw[k][0].y*xw[k][0].y
             + pa.z*xw[k][0].z*xw[k][0].z + pa.w*xw[k][0].w*xw[k][0].w;
        xsB += pb.x*xw[k][1].x*xw[k][1].x + pb.y*xw[k][1].y*xw[k][1].y
             + pb.z*xw[k][1].z*xw[k][1].z + pb.w*xw[k][1].w*xw[k][1].w;
        xsA += pa.x*xw[k][2].x*xw[k][2].x + pa.y*xw[k][2].y*xw[k][2].y
             + pa.z*xw[k][2].z*xw[k][2].z + pa.w*xw[k][2].w*xw[k][2].w;
        xsB += pb.x*xw[k][3].x*xw[k][3].x + pb.y*xw[k][3].y*xw[k][3].y
             + pb.z*xw[k][3].z*xw[k][3].z + pb.w*xw[k][3].w*xw[k][3].w;
        a0[k] = pack8(xw[k][0], xw[k][1]);
        a1[k] = pack8(xw[k][2], xw[k][3]);
    }
    lacc += 0.5f * (xsA + xsB);

    // ---- rg1 compute ----
    lacc -= do_rowgroup(a0, a1, sB, sMusq, low4, q);

    // ---- block reduction, one atomic ----
    lacc += __shfl_xor(lacc, 32); lacc += __shfl_xor(lacc, 16);
    lacc += __shfl_xor(lacc, 8);  lacc += __shfl_xor(lacc, 4);
    lacc += __shfl_xor(lacc, 2);  lacc += __shfl_xor(lacc, 1);
    if (lane == 0) sRed[wave] = lacc;
    __syncthreads();
    if (tid == 0) atomicAdd(out, sRed[0] + sRed[1] + sRed[2] + sRed[3]);
}

extern "C" void kernel_launch(void* const* d_in, const int* in_sizes, int n_in,
                              void* d_out, int out_size, void* d_ws, size_t ws_size,
                              hipStream_t stream) {
    const float* x    = (const float*)d_in[0];
    const float* mu   = (const float*)d_in[1];
    const float* prec = (const float*)d_in[2];
    float* out = (float*)d_out;

    unsigned short* Bp = (unsigned short*)d_ws;                      // 69632 B
    float* musq = (float*)((char*)d_ws + K_MIX * LDSB_STRIDE * 2);   // +1024 B

    hipMemsetAsync(d_out, 0, sizeof(float), stream);
    prep_kernel<<<32, 256, 0, stream>>>(mu, prec, Bp, musq);
    mixture_main<<<N_ROWS / 256, 256, 0, stream>>>(x, Bp, musq, prec, out);
}

// Round 6
// 138.986 us; speedup vs baseline: 1.0256x; 1.0256x over previous
//
#include <hip/hip_runtime.h>
#include <hip/hip_bf16.h>

#define N_ROWS 131072
#define K_MIX  256
#define D_DIM  128
#define LDSB_STRIDE 136            // shorts per B row: 128 + 8 pad
#define B_CHUNKS (K_MIX * LDSB_STRIDE / 8)   // 4352 chunks of 16 B
#define LOG2E 1.4426950408889634f
#define LN2   0.6931471805599453f

typedef float  f32x4  __attribute__((ext_vector_type(4)));
typedef short  bf16x8 __attribute__((ext_vector_type(8)));

__device__ inline bf16x8 pack8(float4 a, float4 b) {
    union { bf16x8 v; __hip_bfloat162 h[4]; } u;
    u.h[0] = __float22bfloat162_rn(make_float2(a.x, a.y));
    u.h[1] = __float22bfloat162_rn(make_float2(a.z, a.w));
    u.h[2] = __float22bfloat162_rn(make_float2(b.x, b.y));
    u.h[3] = __float22bfloat162_rn(make_float2(b.z, b.w));
    return u.v;
}

// -------- prep: ws <- padded bf16(log2e*prec*mu), fp32 0.5*log2e*musq --------
__global__ void prep_kernel(const float* __restrict__ mu,
                            const float* __restrict__ prec,
                            unsigned short* __restrict__ Bp,
                            float* __restrict__ musq)
{
    int idx = blockIdx.x * 256 + threadIdx.x;   // 0..8191 float4s of mu
    int row = idx >> 5;
    int c4  = idx & 31;
    float4 mv = ((const float4*)mu)[idx];
    float4 pv = ((const float4*)prec)[c4];
    float px = mv.x * pv.x, py = mv.y * pv.y, pz = mv.z * pv.z, pw = mv.w * pv.w;
    union { ushort4 u4; __hip_bfloat162 h[2]; } h;
    h.h[0] = __float22bfloat162_rn(make_float2(px * LOG2E, py * LOG2E));
    h.h[1] = __float22bfloat162_rn(make_float2(pz * LOG2E, pw * LOG2E));
    *(ushort4*)&Bp[row * LDSB_STRIDE + c4 * 4] = h.u4;
    if (c4 == 31) {
        bf16x8 z = (bf16x8)0;
        *(bf16x8*)&Bp[row * LDSB_STRIDE + 128] = z;
    }
    float ps = px * mv.x + py * mv.y + pz * mv.z + pw * mv.w;
    ps += __shfl_xor(ps, 1);  ps += __shfl_xor(ps, 2);
    ps += __shfl_xor(ps, 4);  ps += __shfl_xor(ps, 8);
    ps += __shfl_xor(ps, 16);
    if ((threadIdx.x & 31) == 0) musq[row] = 0.5f * LOG2E * ps;
}

// -------- DMA one 4-KB x slice (32 rows x 32 dims fp32) into wave-private LDS --------
__device__ inline void dma4(const char* gp, char* lp) {
    #pragma unroll
    for (int j = 0; j < 4; ++j)
        __builtin_amdgcn_global_load_lds(
            (const __attribute__((address_space(1))) unsigned int*)(gp + j * 4096),
            (__attribute__((address_space(3))) unsigned int*)(lp + j * 1024),
            16, 0, 0);
}

// -------- consume one slice from LDS: xsq partial + A-fragments for k --------
__device__ inline void pack_slice(const float* xb, const float* sPrec, int k,
                                  int low4, int q, bf16x8& o0, bf16x8& o1, float& xs)
{
    const float* r0 = xb + low4 * 32 + q * 8;
    const float* r1 = r0 + 16 * 32;
    float4 u0 = *(const float4*)r0;
    float4 u1 = *(const float4*)(r0 + 4);
    float4 v0 = *(const float4*)r1;
    float4 v1 = *(const float4*)(r1 + 4);
    float4 pa = *(const float4*)&sPrec[k * 32 + q * 8];
    float4 pb = *(const float4*)&sPrec[k * 32 + q * 8 + 4];
    xs += pa.x*u0.x*u0.x + pa.y*u0.y*u0.y + pa.z*u0.z*u0.z + pa.w*u0.w*u0.w
        + pb.x*u1.x*u1.x + pb.y*u1.y*u1.y + pb.z*u1.z*u1.z + pb.w*u1.w*u1.w
        + pa.x*v0.x*v0.x + pa.y*v0.y*v0.y + pa.z*v0.z*v0.z + pa.w*v0.w*v0.w
        + pb.x*v1.x*v1.x + pb.y*v1.y*v1.y + pb.z*v1.z*v1.z + pb.w*v1.w*v1.w;
    o0 = pack8(u0, u1);
    o1 = pack8(v0, v1);
}

// -------- per-rowgroup: MFMA over 2 column halves + online LSE (log2 domain) --------
__device__ inline float do_rowgroup(const bf16x8* a0, const bf16x8* a1,
                                    const unsigned short* sB, const float* sMusq,
                                    int low4, int q)
{
    float m_run[2][4], s_run[2][4];

    #pragma unroll 1
    for (int h = 0; h < 2; ++h) {
        f32x4 acc[2][8];
        #pragma unroll
        for (int c = 0; c < 8; ++c) {
            float mneg = sMusq[(h * 8 + c) * 16 + low4];   // = -0.5*log2e*musq[col]
            #pragma unroll
            for (int i = 0; i < 4; ++i) { acc[0][c][i] = mneg; acc[1][c][i] = mneg; }
        }

        #pragma unroll
        for (int k = 0; k < 4; ++k) {
            #pragma unroll
            for (int c = 0; c < 8; ++c) {
                const unsigned short* bp =
                    &sB[((h * 8 + c) * 16 + low4) * LDSB_STRIDE + k * 32 + q * 8];
                bf16x8 b = *(const bf16x8*)bp;   // ds_read_b128
                acc[0][c] = __builtin_amdgcn_mfma_f32_16x16x32_bf16(a0[k], b, acc[0][c], 0, 0, 0);
                acc[1][c] = __builtin_amdgcn_mfma_f32_16x16x32_bf16(a1[k], b, acc[1][c], 0, 0, 0);
            }
        }

        #pragma unroll
        for (int m = 0; m < 2; ++m) {
            #pragma unroll
            for (int i = 0; i < 4; ++i) {
                float v0 = acc[m][0][i], v1 = acc[m][1][i];
                float v2 = acc[m][2][i], v3 = acc[m][3][i];
                float v4 = acc[m][4][i], v5 = acc[m][5][i];
                float v6 = acc[m][6][i], v7 = acc[m][7][i];
                float hmax = fmaxf(fmaxf(fmaxf(v0, v1), fmaxf(v2, v3)),
                                   fmaxf(fmaxf(v4, v5), fmaxf(v6, v7)));
                float hsum = __builtin_amdgcn_exp2f(v0 - hmax) + __builtin_amdgcn_exp2f(v1 - hmax)
                           + __builtin_amdgcn_exp2f(v2 - hmax) + __builtin_amdgcn_exp2f(v3 - hmax)
                           + __builtin_amdgcn_exp2f(v4 - hmax) + __builtin_amdgcn_exp2f(v5 - hmax)
                           + __builtin_amdgcn_exp2f(v6 - hmax) + __builtin_amdgcn_exp2f(v7 - hmax);
                if (h == 0) {
                    m_run[m][i] = hmax; s_run[m][i] = hsum;
                } else {
                    float mr = m_run[m][i];
                    float mn = fmaxf(mr, hmax);
                    s_run[m][i] = s_run[m][i] * __builtin_amdgcn_exp2f(mr - mn)
                                + hsum        * __builtin_amdgcn_exp2f(hmax - mn);
                    m_run[m][i] = mn;
                }
            }
        }
    }

    float lsum = 0.f;
    #pragma unroll
    for (int m = 0; m < 2; ++m) {
        #pragma unroll
        for (int i = 0; i < 4; ++i) {
            float mr = m_run[m][i], sr = s_run[m][i];
            #pragma unroll
            for (int step = 1; step <= 8; step <<= 1) {
                float mo = __shfl_xor(mr, step);
                float so = __shfl_xor(sr, step);
                float mn = fmaxf(mr, mo);
                sr = sr * __builtin_amdgcn_exp2f(mr - mn)
                   + so * __builtin_amdgcn_exp2f(mo - mn);
                mr = mn;
            }
            if (low4 == 0) lsum += LN2 * (mr + __builtin_amdgcn_logf(sr));
        }
    }
    return lsum;
}

// ---------------- main: 512 threads, 512 rows/block, 1 block/CU ----------------
__global__ __launch_bounds__(512, 2)
void mixture_main(const float* __restrict__ x,
                  const unsigned short* __restrict__ Bp,
                  const float* __restrict__ musqg,
                  const float* __restrict__ prec,
                  float* __restrict__ out)
{
    __shared__ __align__(16) unsigned short sB[K_MIX * LDSB_STRIDE];   // 69632 B
    __shared__ __align__(16) char sX[8][2][4096];                      // 65536 B
    __shared__ float sMusq[K_MIX];
    __shared__ float sPrec[D_DIM];
    __shared__ float sRed[8];

    const int tid  = threadIdx.x;
    const int lane = tid & 63;
    const int wave = tid >> 6;
    const int low4 = lane & 15;
    const int q    = lane >> 4;

    // ---- B staging via DMA (lane-contiguous image; no VGPR round-trip) ----
    #pragma unroll
    for (int i = 0; i < 8; ++i) {
        int chunk = i * 512 + wave * 64 + lane;
        __builtin_amdgcn_global_load_lds(
            (const __attribute__((address_space(1))) unsigned int*)(Bp + (size_t)chunk * 8),
            (__attribute__((address_space(3))) unsigned int*)(sB + (size_t)chunk * 8),
            16, 0, 0);
    }
    if (wave < 4) {   // tail: chunks 4096..4351
        int chunk = 4096 + wave * 64 + lane;
        __builtin_amdgcn_global_load_lds(
            (const __attribute__((address_space(1))) unsigned int*)(Bp + (size_t)chunk * 8),
            (__attribute__((address_space(3))) unsigned int*)(sB + (size_t)chunk * 8),
            16, 0, 0);
    }
    if (tid < K_MIX) sMusq[tid] = -musqg[tid];
    if (tid < D_DIM) sPrec[tid] = prec[tid];
    __syncthreads();   // drains all vmcnt (B DMA complete) — clean slate for slice counting

    // per-lane global base: row = blockBase + wave*32 + (lane>>3), chunk (lane&7)*16 B
    const char* gb = (const char*)x
        + ((size_t)blockIdx.x * 512 + wave * 32 + (lane >> 3)) * 512
        + (size_t)(lane & 7) * 16;
    char* lb0 = &sX[wave][0][0] + lane * 16;
    char* lb1 = &sX[wave][1][0] + lane * 16;
    const float* xb0 = (const float*)&sX[wave][0][0];
    const float* xb1 = (const float*)&sX[wave][1][0];

    dma4(gb + 0 * 128, lb0);            // rg0 k0
    dma4(gb + 1 * 128, lb1);            // rg0 k1

    float lacc = 0.f, xs = 0.f;
    bf16x8 a0[4], a1[4];

    // ---- rowgroup 0: stream 4 slices, keep next DMAs in flight ----
    __builtin_amdgcn_s_waitcnt(0x0F74);                      // rg0k0 done
    pack_slice(xb0, sPrec, 0, low4, q, a0[0], a1[0], xs);
    dma4(gb + 2 * 128, lb0);            // rg0 k2
    __builtin_amdgcn_s_waitcnt(0x0F74);                      // rg0k1 done
    pack_slice(xb1, sPrec, 1, low4, q, a0[1], a1[1], xs);
    dma4(gb + 3 * 128, lb1);            // rg0 k3
    __builtin_amdgcn_s_waitcnt(0x0F74);                      // rg0k2 done
    pack_slice(xb0, sPrec, 2, low4, q, a0[2], a1[2], xs);
    dma4(gb + 131072 + 0 * 128, lb0);   // rg1 k0 (in flight during rg0 compute)
    __builtin_amdgcn_s_waitcnt(0x0F74);                      // rg0k3 done
    pack_slice(xb1, sPrec, 3, low4, q, a0[3], a1[3], xs);
    dma4(gb + 131072 + 1 * 128, lb1);   // rg1 k1 (in flight during rg0 compute)

    lacc += 0.5f * xs; xs = 0.f;
    lacc -= do_rowgroup(a0, a1, sB, sMusq, low4, q);

    // ---- rowgroup 1 ----
    __builtin_amdgcn_s_waitcnt(0x0F74);                      // rg1k0 done
    pack_slice(xb0, sPrec, 0, low4, q, a0[0], a1[0], xs);
    dma4(gb + 131072 + 2 * 128, lb0);   // rg1 k2
    __builtin_amdgcn_s_waitcnt(0x0F74);                      // rg1k1 done
    pack_slice(xb1, sPrec, 1, low4, q, a0[1], a1[1], xs);
    dma4(gb + 131072 + 3 * 128, lb1);   // rg1 k3
    __builtin_amdgcn_s_waitcnt(0x0F74);                      // rg1k2 done
    pack_slice(xb0, sPrec, 2, low4, q, a0[2], a1[2], xs);
    __builtin_amdgcn_s_waitcnt(0x0F70);                      // rg1k3 done (vmcnt 0)
    pack_slice(xb1, sPrec, 3, low4, q, a0[3], a1[3], xs);

    lacc += 0.5f * xs;
    lacc -= do_rowgroup(a0, a1, sB, sMusq, low4, q);

    // ---- block reduction, one atomic ----
    lacc += __shfl_xor(lacc, 32); lacc += __shfl_xor(lacc, 16);
    lacc += __shfl_xor(lacc, 8);  lacc += __shfl_xor(lacc, 4);
    lacc += __shfl_xor(lacc, 2);  lacc += __shfl_xor(lacc, 1);
    if (lane == 0) sRed[wave] = lacc;
    __syncthreads();
    if (tid == 0) {
        float t = 0.f;
        #pragma unroll
        for (int i = 0; i < 8; ++i) t += sRed[i];
        atomicAdd(out, t);
    }
}

extern "C" void kernel_launch(void* const* d_in, const int* in_sizes, int n_in,
                              void* d_out, int out_size, void* d_ws, size_t ws_size,
                              hipStream_t stream) {
    const float* x    = (const float*)d_in[0];
    const float* mu   = (const float*)d_in[1];
    const float* prec = (const float*)d_in[2];
    float* out = (float*)d_out;

    unsigned short* Bp = (unsigned short*)d_ws;                      // 69632 B
    float* musq = (float*)((char*)d_ws + K_MIX * LDSB_STRIDE * 2);   // +1024 B

    hipMemsetAsync(d_out, 0, sizeof(float), stream);
    prep_kernel<<<32, 256, 0, stream>>>(mu, prec, Bp, musq);
    mixture_main<<<N_ROWS / 512, 512, 0, stream>>>(x, Bp, musq, prec, out);
}

// Round 7
// 133.246 us; speedup vs baseline: 1.0698x; 1.0431x over previous
//
#include <hip/hip_runtime.h>
#include <hip/hip_bf16.h>

#define N_ROWS 131072
#define K_MIX  256
#define D_DIM  128
#define LDSB_STRIDE 136            // shorts per B row: 128 + 8 pad
#define B_CHUNKS (K_MIX * LDSB_STRIDE / 8)   // 4352 chunks of 16 B
#define LOG2E 1.4426950408889634f
#define LN2   0.6931471805599453f

typedef float  f32x4  __attribute__((ext_vector_type(4)));
typedef short  bf16x8 __attribute__((ext_vector_type(8)));

__device__ inline bf16x8 pack8(float4 a, float4 b) {
    union { bf16x8 v; __hip_bfloat162 h[4]; } u;
    u.h[0] = __float22bfloat162_rn(make_float2(a.x, a.y));
    u.h[1] = __float22bfloat162_rn(make_float2(a.z, a.w));
    u.h[2] = __float22bfloat162_rn(make_float2(b.x, b.y));
    u.h[3] = __float22bfloat162_rn(make_float2(b.z, b.w));
    return u.v;
}

// -------- prep: ws <- padded bf16(log2e*prec*mu), fp32 0.5*log2e*musq --------
__global__ void prep_kernel(const float* __restrict__ mu,
                            const float* __restrict__ prec,
                            unsigned short* __restrict__ Bp,
                            float* __restrict__ musq)
{
    int idx = blockIdx.x * 256 + threadIdx.x;   // 0..8191 float4s of mu
    int row = idx >> 5;
    int c4  = idx & 31;
    float4 mv = ((const float4*)mu)[idx];
    float4 pv = ((const float4*)prec)[c4];
    float px = mv.x * pv.x, py = mv.y * pv.y, pz = mv.z * pv.z, pw = mv.w * pv.w;
    union { ushort4 u4; __hip_bfloat162 h[2]; } h;
    h.h[0] = __float22bfloat162_rn(make_float2(px * LOG2E, py * LOG2E));
    h.h[1] = __float22bfloat162_rn(make_float2(pz * LOG2E, pw * LOG2E));
    *(ushort4*)&Bp[row * LDSB_STRIDE + c4 * 4] = h.u4;
    if (c4 == 31) {
        bf16x8 z = (bf16x8)0;
        *(bf16x8*)&Bp[row * LDSB_STRIDE + 128] = z;
    }
    float ps = px * mv.x + py * mv.y + pz * mv.z + pw * mv.w;
    ps += __shfl_xor(ps, 1);  ps += __shfl_xor(ps, 2);
    ps += __shfl_xor(ps, 4);  ps += __shfl_xor(ps, 8);
    ps += __shfl_xor(ps, 16);
    if ((threadIdx.x & 31) == 0) musq[row] = 0.5f * LOG2E * ps;
}

// -------- DMA one 4-KB x slice (32 rows x 32 dims fp32) into wave-private LDS --------
// LDS layout is swizzled: granule position p of row R holds global granule (p-R)&7.
// The swizzle is applied on the GLOBAL side (gb already includes the per-lane rotate).
__device__ inline void dma4(const char* gp, char* lp) {
    #pragma unroll
    for (int j = 0; j < 4; ++j)
        __builtin_amdgcn_global_load_lds(
            (const __attribute__((address_space(1))) unsigned int*)(gp + j * 4096),
            (__attribute__((address_space(3))) unsigned int*)(lp + j * 1024),
            16, 0, 0);
}

// -------- consume one slice from LDS: xsq partial + A-fragments for k --------
__device__ inline void pack_slice(const float* xb, const float* sPrec, int k,
                                  int low4, int q, bf16x8& o0, bf16x8& o1, float& xs)
{
    // swizzled granule positions: global granule 2q / 2q+1 live at (d+row)&7
    const int p0 = ((2 * q + low4) & 7) * 4;
    const int p1 = ((2 * q + 1 + low4) & 7) * 4;
    const float* r0 = xb + low4 * 32;
    const float* r1 = r0 + 16 * 32;
    float4 u0 = *(const float4*)(r0 + p0);
    float4 u1 = *(const float4*)(r0 + p1);
    float4 v0 = *(const float4*)(r1 + p0);
    float4 v1 = *(const float4*)(r1 + p1);
    float4 pa = *(const float4*)&sPrec[k * 32 + q * 8];
    float4 pb = *(const float4*)&sPrec[k * 32 + q * 8 + 4];
    xs += pa.x*u0.x*u0.x + pa.y*u0.y*u0.y + pa.z*u0.z*u0.z + pa.w*u0.w*u0.w
        + pb.x*u1.x*u1.x + pb.y*u1.y*u1.y + pb.z*u1.z*u1.z + pb.w*u1.w*u1.w
        + pa.x*v0.x*v0.x + pa.y*v0.y*v0.y + pa.z*v0.z*v0.z + pa.w*v0.w*v0.w
        + pb.x*v1.x*v1.x + pb.y*v1.y*v1.y + pb.z*v1.z*v1.z + pb.w*v1.w*v1.w;
    o0 = pack8(u0, u1);
    o1 = pack8(v0, v1);
}

// -------- per-rowgroup: MFMA over 4 column quarters + online LSE (log2 domain) --------
__device__ inline float do_rowgroup(const bf16x8* a0, const bf16x8* a1,
                                    const unsigned short* sB, const float* sMusq,
                                    int low4, int q)
{
    float m_run[2][4], s_run[2][4];

    #pragma unroll 1
    for (int h = 0; h < 4; ++h) {
        f32x4 acc[2][4];
        #pragma unroll
        for (int c = 0; c < 4; ++c) {
            float mneg = sMusq[(h * 4 + c) * 16 + low4];   // = -0.5*log2e*musq[col]
            #pragma unroll
            for (int i = 0; i < 4; ++i) { acc[0][c][i] = mneg; acc[1][c][i] = mneg; }
        }

        #pragma unroll
        for (int k = 0; k < 4; ++k) {
            #pragma unroll
            for (int c = 0; c < 4; ++c) {
                const unsigned short* bp =
                    &sB[((h * 4 + c) * 16 + low4) * LDSB_STRIDE + k * 32 + q * 8];
                bf16x8 b = *(const bf16x8*)bp;   // ds_read_b128
                acc[0][c] = __builtin_amdgcn_mfma_f32_16x16x32_bf16(a0[k], b, acc[0][c], 0, 0, 0);
                acc[1][c] = __builtin_amdgcn_mfma_f32_16x16x32_bf16(a1[k], b, acc[1][c], 0, 0, 0);
            }
        }

        #pragma unroll
        for (int m = 0; m < 2; ++m) {
            #pragma unroll
            for (int i = 0; i < 4; ++i) {
                float v0 = acc[m][0][i], v1 = acc[m][1][i];
                float v2 = acc[m][2][i], v3 = acc[m][3][i];
                float hmax = fmaxf(fmaxf(v0, v1), fmaxf(v2, v3));
                float hsum = __builtin_amdgcn_exp2f(v0 - hmax) + __builtin_amdgcn_exp2f(v1 - hmax)
                           + __builtin_amdgcn_exp2f(v2 - hmax) + __builtin_amdgcn_exp2f(v3 - hmax);
                if (h == 0) {
                    m_run[m][i] = hmax; s_run[m][i] = hsum;
                } else {
                    float mr = m_run[m][i];
                    float mn = fmaxf(mr, hmax);
                    s_run[m][i] = s_run[m][i] * __builtin_amdgcn_exp2f(mr - mn)
                                + hsum        * __builtin_amdgcn_exp2f(hmax - mn);
                    m_run[m][i] = mn;
                }
            }
        }
    }

    float lsum = 0.f;
    #pragma unroll
    for (int m = 0; m < 2; ++m) {
        #pragma unroll
        for (int i = 0; i < 4; ++i) {
            float mr = m_run[m][i], sr = s_run[m][i];
            #pragma unroll
            for (int step = 1; step <= 8; step <<= 1) {
                float mo = __shfl_xor(mr, step);
                float so = __shfl_xor(sr, step);
                float mn = fmaxf(mr, mo);
                sr = sr * __builtin_amdgcn_exp2f(mr - mn)
                   + so * __builtin_amdgcn_exp2f(mo - mn);
                mr = mn;
            }
            if (low4 == 0) lsum += LN2 * (mr + __builtin_amdgcn_logf(sr));
        }
    }
    return lsum;
}

// ---------------- main: 512 threads, 512 rows/block, 1 block/CU ----------------
__global__ __launch_bounds__(512, 2)
void mixture_main(const float* __restrict__ x,
                  const unsigned short* __restrict__ Bp,
                  const float* __restrict__ musqg,
                  const float* __restrict__ prec,
                  float* __restrict__ out)
{
    __shared__ __align__(16) unsigned short sB[K_MIX * LDSB_STRIDE];   // 69632 B
    __shared__ __align__(16) char sX[8][2][4096];                      // 65536 B
    __shared__ float sMusq[K_MIX];
    __shared__ float sPrec[D_DIM];
    __shared__ float sRed[8];

    const int tid  = threadIdx.x;
    const int lane = tid & 63;
    const int wave = tid >> 6;
    const int low4 = lane & 15;
    const int q    = lane >> 4;

    // ---- B staging via DMA (lane-contiguous image; no VGPR round-trip) ----
    #pragma unroll
    for (int i = 0; i < 8; ++i) {
        int chunk = i * 512 + wave * 64 + lane;
        __builtin_amdgcn_global_load_lds(
            (const __attribute__((address_space(1))) unsigned int*)(Bp + (size_t)chunk * 8),
            (__attribute__((address_space(3))) unsigned int*)(sB + (size_t)chunk * 8),
            16, 0, 0);
    }
    if (wave < 4) {   // tail: chunks 4096..4351
        int chunk = 4096 + wave * 64 + lane;
        __builtin_amdgcn_global_load_lds(
            (const __attribute__((address_space(1))) unsigned int*)(Bp + (size_t)chunk * 8),
            (__attribute__((address_space(3))) unsigned int*)(sB + (size_t)chunk * 8),
            16, 0, 0);
    }
    if (tid < K_MIX) sMusq[tid] = -musqg[tid];
    if (tid < D_DIM) sPrec[tid] = prec[tid];
    __syncthreads();   // drains all vmcnt (B DMA complete) — clean slate for slice counting

    // per-lane global base with swizzle rotate:
    //   row = blockBase + wave*32 + (lane>>3); granule d = ((lane&7) - (lane>>3)) & 7
    const char* gb = (const char*)x
        + ((size_t)blockIdx.x * 512 + wave * 32 + (lane >> 3)) * 512
        + (size_t)(((lane & 7) - (lane >> 3)) & 7) * 16;
    char* lb0 = &sX[wave][0][0] + lane * 16;
    char* lb1 = &sX[wave][1][0] + lane * 16;
    const float* xb0 = (const float*)&sX[wave][0][0];
    const float* xb1 = (const float*)&sX[wave][1][0];

    dma4(gb + 0 * 128, lb0);            // rg0 k0
    dma4(gb + 1 * 128, lb1);            // rg0 k1

    float lacc = 0.f, xs = 0.f;
    bf16x8 a0[4], a1[4];

    // ---- rowgroup 0: stream 4 slices, keep next DMAs in flight ----
    __builtin_amdgcn_s_waitcnt(0x0F74);                      // rg0k0 done (vmcnt 4)
    pack_slice(xb0, sPrec, 0, low4, q, a0[0], a1[0], xs);
    dma4(gb + 2 * 128, lb0);            // rg0 k2
    __builtin_amdgcn_s_waitcnt(0x0F74);                      // rg0k1 done
    pack_slice(xb1, sPrec, 1, low4, q, a0[1], a1[1], xs);
    dma4(gb + 3 * 128, lb1);            // rg0 k3
    __builtin_amdgcn_s_waitcnt(0x0F74);                      // rg0k2 done
    pack_slice(xb0, sPrec, 2, low4, q, a0[2], a1[2], xs);
    dma4(gb + 131072 + 0 * 128, lb0);   // rg1 k0 (in flight during rg0 compute)
    __builtin_amdgcn_s_waitcnt(0x0F74);                      // rg0k3 done
    pack_slice(xb1, sPrec, 3, low4, q, a0[3], a1[3], xs);
    dma4(gb + 131072 + 1 * 128, lb1);   // rg1 k1 (in flight during rg0 compute)

    lacc += 0.5f * xs; xs = 0.f;
    lacc -= do_rowgroup(a0, a1, sB, sMusq, low4, q);

    // ---- rowgroup 1 ----
    __builtin_amdgcn_s_waitcnt(0x0F74);                      // rg1k0 done
    pack_slice(xb0, sPrec, 0, low4, q, a0[0], a1[0], xs);
    dma4(gb + 131072 + 2 * 128, lb0);   // rg1 k2
    __builtin_amdgcn_s_waitcnt(0x0F74);                      // rg1k1 done
    pack_slice(xb1, sPrec, 1, low4, q, a0[1], a1[1], xs);
    dma4(gb + 131072 + 3 * 128, lb1);   // rg1 k3
    __builtin_amdgcn_s_waitcnt(0x0F74);                      // rg1k2 done
    pack_slice(xb0, sPrec, 2, low4, q, a0[2], a1[2], xs);
    __builtin_amdgcn_s_waitcnt(0x0F70);                      // rg1k3 done (vmcnt 0)
    pack_slice(xb1, sPrec, 3, low4, q, a0[3], a1[3], xs);

    lacc += 0.5f * xs;
    lacc -= do_rowgroup(a0, a1, sB, sMusq, low4, q);

    // ---- block reduction, one atomic ----
    lacc += __shfl_xor(lacc, 32); lacc += __shfl_xor(lacc, 16);
    lacc += __shfl_xor(lacc, 8);  lacc += __shfl_xor(lacc, 4);
    lacc += __shfl_xor(lacc, 2);  lacc += __shfl_xor(lacc, 1);
    if (lane == 0) sRed[wave] = lacc;
    __syncthreads();
    if (tid == 0) {
        float t = 0.f;
        #pragma unroll
        for (int i = 0; i < 8; ++i) t += sRed[i];
        atomicAdd(out, t);
    }
}

extern "C" void kernel_launch(void* const* d_in, const int* in_sizes, int n_in,
                              void* d_out, int out_size, void* d_ws, size_t ws_size,
                              hipStream_t stream) {
    const float* x    = (const float*)d_in[0];
    const float* mu   = (const float*)d_in[1];
    const float* prec = (const float*)d_in[2];
    float* out = (float*)d_out;

    unsigned short* Bp = (unsigned short*)d_ws;                      // 69632 B
    float* musq = (float*)((char*)d_ws + K_MIX * LDSB_STRIDE * 2);   // +1024 B

    hipMemsetAsync(d_out, 0, sizeof(float), stream);
    prep_kernel<<<32, 256, 0, stream>>>(mu, prec, Bp, musq);
    mixture_main<<<N_ROWS / 512, 512, 0, stream>>>(x, Bp, musq, prec, out);
}

// Round 8
// 124.907 us; speedup vs baseline: 1.1412x; 1.0668x over previous
//
#include <hip/hip_runtime.h>
#include <hip/hip_bf16.h>

#define N_ROWS 131072
#define K_MIX  256
#define D_DIM  128
#define LOG2E 1.4426950408889634f
#define LN2   0.6931471805599453f

typedef float  f32x4  __attribute__((ext_vector_type(4)));
typedef short  bf16x8 __attribute__((ext_vector_type(8)));

__device__ inline bf16x8 pack8(float4 a, float4 b) {
    union { bf16x8 v; __hip_bfloat162 h[4]; } u;
    u.h[0] = __float22bfloat162_rn(make_float2(a.x, a.y));
    u.h[1] = __float22bfloat162_rn(make_float2(a.z, a.w));
    u.h[2] = __float22bfloat162_rn(make_float2(b.x, b.y));
    u.h[3] = __float22bfloat162_rn(make_float2(b.z, b.w));
    return u.v;
}

// ---- prep 1: msq[col] = -0.5*log2e * sum_d prec[d]*mu[col][d]^2 ----
__global__ void prep_musq(const float* __restrict__ mu, const float* __restrict__ prec,
                          float* __restrict__ msq)
{
    int col = threadIdx.x;
    const float4* m4 = (const float4*)(mu + (size_t)col * D_DIM);
    const float4* p4 = (const float4*)prec;
    float s = 0.f;
    #pragma unroll 8
    for (int i = 0; i < 32; ++i) {
        float4 m = m4[i], p = p4[i];
        s += p.x*m.x*m.x + p.y*m.y*m.y + p.z*m.z*m.z + p.w*m.w*m.w;
    }
    msq[col] = -0.5f * LOG2E * s;
}

// ---- prep 2: Bf in MFMA B-fragment order: frag(w,k,cg,lane) = bf16x8 ----
// col = w*64 + cg*16 + (lane&15), d = k*32 + (lane>>4)*8 + 0..7, val = log2e*prec*mu
__global__ void prep_frag(const float* __restrict__ mu, const float* __restrict__ prec,
                          unsigned short* __restrict__ Bf)
{
    int g = blockIdx.x * 256 + threadIdx.x;       // 0..4095
    int lane = g & 63, cg = (g >> 6) & 3, k = (g >> 8) & 3, w = (g >> 10) & 3;
    int col = w*64 + cg*16 + (lane & 15);
    int d0 = k*32 + (lane >> 4)*8;
    const float* mp = mu + (size_t)col * D_DIM + d0;
    const float* pp = prec + d0;
    union { bf16x8 v; __hip_bfloat162 h[4]; } u;
    #pragma unroll
    for (int j = 0; j < 4; ++j) {
        float e0 = LOG2E * pp[2*j]     * mp[2*j];
        float e1 = LOG2E * pp[2*j + 1] * mp[2*j + 1];
        u.h[j] = __float22bfloat162_rn(make_float2(e0, e1));
    }
    *(bf16x8*)(Bf + (size_t)g * 8) = u.v;
}

// ---------------- main: 256 thr, 4 waves x 64 cols, 8 tiles of 32 rows ----------------
__global__ __launch_bounds__(256, 2)
void mixture_main(const float* __restrict__ x,
                  const unsigned short* __restrict__ Bf,
                  const float* __restrict__ msq,
                  const float* __restrict__ prec,
                  float* __restrict__ out)
{
    __shared__ __align__(16) float sXT[2][4096];   // two 16-KB x tiles (granule-swizzled)
    __shared__ float sMS[4 * 32 * 2];              // [wave][row][(m,s)]
    __shared__ float sPrec[D_DIM];

    const int tid  = threadIdx.x;
    const int lane = tid & 63;
    const int w    = tid >> 6;
    const int low4 = lane & 15;
    const int q    = lane >> 4;

    // ---- B fragments -> registers, issued FIRST (vmcnt ordering) ----
    bf16x8 Bfr[4][4];
    #pragma unroll
    for (int k = 0; k < 4; ++k)
        #pragma unroll
        for (int cg = 0; cg < 4; ++cg)
            Bfr[k][cg] = *(const bf16x8*)(Bf + (size_t)(((w*4 + k)*4 + cg)*64 + lane) * 8);
    float mneg[4];
    #pragma unroll
    for (int cg = 0; cg < 4; ++cg) mneg[cg] = msq[w*64 + cg*16 + low4];

    if (tid < D_DIM) sPrec[tid] = prec[tid];

    // ---- per-lane DMA offsets (tile-invariant). Swizzle: pos p of row r holds
    // global granule (p-r)&31; DMA instr j covers rows 2j,2j+1, p = lane&31.
    int goff[4], loff[4];
    {
        int p = lane & 31;
        #pragma unroll
        for (int jj = 0; jj < 4; ++jj) {
            int j = w*4 + jj;
            int r = 2*j + (lane >> 5);
            goff[jj] = r*512 + (((p - r) & 31) << 4);
            loff[jj] = j*1024 + lane*16;
        }
    }
    const char* gtile = (const char*)x + (size_t)blockIdx.x * 131072;  // 256 rows * 512 B
    char* lbase = (char*)&sXT[0][0];

    // issue DMA for tiles 0 and 1 (after B/mneg loads)
    #pragma unroll
    for (int jj = 0; jj < 4; ++jj)
        __builtin_amdgcn_global_load_lds(
            (const __attribute__((address_space(1))) unsigned int*)(gtile + goff[jj]),
            (__attribute__((address_space(3))) unsigned int*)(lbase + loff[jj]), 16, 0, 0);
    #pragma unroll
    for (int jj = 0; jj < 4; ++jj)
        __builtin_amdgcn_global_load_lds(
            (const __attribute__((address_space(1))) unsigned int*)(gtile + 16384 + goff[jj]),
            (__attribute__((address_space(3))) unsigned int*)(lbase + 16384 + loff[jj]), 16, 0, 0);

    float lacc = 0.f;

    #pragma unroll 1
    for (int t = 0; t < 8; ++t) {
        // own DMA for tile t retired (t+1 stays in flight) + lgkm drained, then barrier
        if (t < 7) __builtin_amdgcn_s_waitcnt(0x0F74);   // vmcnt(4)
        else       __builtin_amdgcn_s_waitcnt(0x0F70);   // vmcnt(0)
        __builtin_amdgcn_s_waitcnt(0xC07F);              // lgkmcnt(0)
        __asm__ volatile("s_barrier" ::: "memory");

        const float* buf = &sXT[t & 1][0];

        f32x4 acc[2][4];
        #pragma unroll
        for (int cg = 0; cg < 4; ++cg) {
            #pragma unroll
            for (int i = 0; i < 4; ++i) { acc[0][cg][i] = mneg[cg]; acc[1][cg][i] = mneg[cg]; }
        }

        float xs = 0.f;
        #pragma unroll
        for (int k = 0; k < 4; ++k) {
            int g0  = 8*k + 2*q;
            int p0  = (g0 + low4) & 31;
            int p1  = (g0 + 1 + low4) & 31;
            int p0b = (p0 + 16) & 31;
            int p1b = (p1 + 16) & 31;
            const float* r0 = buf + low4 * 128;
            const float* r1 = buf + (low4 + 16) * 128;
            float4 u0 = *(const float4*)(r0 + p0  * 4);
            float4 u1 = *(const float4*)(r0 + p1  * 4);
            float4 v0 = *(const float4*)(r1 + p0b * 4);
            float4 v1 = *(const float4*)(r1 + p1b * 4);
            if (w == 0) {   // wave 0 covers every (row,dim) of the tile exactly once
                float4 pa = *(const float4*)&sPrec[k*32 + q*8];
                float4 pb = *(const float4*)&sPrec[k*32 + q*8 + 4];
                xs += pa.x*u0.x*u0.x + pa.y*u0.y*u0.y + pa.z*u0.z*u0.z + pa.w*u0.w*u0.w
                    + pb.x*u1.x*u1.x + pb.y*u1.y*u1.y + pb.z*u1.z*u1.z + pb.w*u1.w*u1.w
                    + pa.x*v0.x*v0.x + pa.y*v0.y*v0.y + pa.z*v0.z*v0.z + pa.w*v0.w*v0.w
                    + pb.x*v1.x*v1.x + pb.y*v1.y*v1.y + pb.z*v1.z*v1.z + pb.w*v1.w*v1.w;
            }
            bf16x8 a0 = pack8(u0, u1);
            bf16x8 a1 = pack8(v0, v1);
            #pragma unroll
            for (int cg = 0; cg < 4; ++cg) {
                acc[0][cg] = __builtin_amdgcn_mfma_f32_16x16x32_bf16(a0, Bfr[k][cg], acc[0][cg], 0, 0, 0);
                acc[1][cg] = __builtin_amdgcn_mfma_f32_16x16x32_bf16(a1, Bfr[k][cg], acc[1][cg], 0, 0, 0);
            }
        }
        lacc += 0.5f * xs;   // nonzero only in wave 0

        // ---- per-row (m,s) over this wave's 64 cols; write to sMS ----
        #pragma unroll
        for (int m = 0; m < 2; ++m) {
            #pragma unroll
            for (int i = 0; i < 4; ++i) {
                float v0 = acc[m][0][i], v1 = acc[m][1][i];
                float v2 = acc[m][2][i], v3 = acc[m][3][i];
                float mx = fmaxf(fmaxf(v0, v1), fmaxf(v2, v3));
                float ss = __builtin_amdgcn_exp2f(v0 - mx) + __builtin_amdgcn_exp2f(v1 - mx)
                         + __builtin_amdgcn_exp2f(v2 - mx) + __builtin_amdgcn_exp2f(v3 - mx);
                #pragma unroll
                for (int st = 1; st <= 8; st <<= 1) {
                    float mo = __shfl_xor(mx, st);
                    float so = __shfl_xor(ss, st);
                    float mn = fmaxf(mx, mo);
                    ss = ss * __builtin_amdgcn_exp2f(mx - mn) + so * __builtin_amdgcn_exp2f(mo - mn);
                    mx = mn;
                }
                if (low4 == 0) {
                    int row = m*16 + q*4 + i;
                    *(float2*)&sMS[(w*32 + row)*2] = make_float2(mx, ss);
                }
            }
        }

        __builtin_amdgcn_s_waitcnt(0xC07F);              // lgkmcnt(0): sMS visible
        __asm__ volatile("s_barrier" ::: "memory");      // also: all packs of tile t done

        if (t < 6) {   // refill the just-freed buffer with tile t+2
            #pragma unroll
            for (int jj = 0; jj < 4; ++jj)
                __builtin_amdgcn_global_load_lds(
                    (const __attribute__((address_space(1))) unsigned int*)(gtile + (size_t)(t+2)*16384 + goff[jj]),
                    (__attribute__((address_space(3))) unsigned int*)(lbase + (t & 1)*16384 + loff[jj]), 16, 0, 0);
        }

        if (tid < 32) {   // merge the 4 waves' (m,s) for row=tid, accumulate lse
            float2 a = *(const float2*)&sMS[(0*32 + tid)*2];
            float2 b = *(const float2*)&sMS[(1*32 + tid)*2];
            float2 c = *(const float2*)&sMS[(2*32 + tid)*2];
            float2 d = *(const float2*)&sMS[(3*32 + tid)*2];
            float mx = fmaxf(fmaxf(a.x, b.x), fmaxf(c.x, d.x));
            float ss = a.y * __builtin_amdgcn_exp2f(a.x - mx)
                     + b.y * __builtin_amdgcn_exp2f(b.x - mx)
                     + c.y * __builtin_amdgcn_exp2f(c.x - mx)
                     + d.y * __builtin_amdgcn_exp2f(d.x - mx);
            lacc -= LN2 * (mx + __builtin_amdgcn_logf(ss));
        }
    }

    // ---- every contribution lives in wave 0 ----
    if (w == 0) {
        lacc += __shfl_xor(lacc, 32); lacc += __shfl_xor(lacc, 16);
        lacc += __shfl_xor(lacc, 8);  lacc += __shfl_xor(lacc, 4);
        lacc += __shfl_xor(lacc, 2);  lacc += __shfl_xor(lacc, 1);
        if (lane == 0) atomicAdd(out, lacc);
    }
}

extern "C" void kernel_launch(void* const* d_in, const int* in_sizes, int n_in,
                              void* d_out, int out_size, void* d_ws, size_t ws_size,
                              hipStream_t stream) {
    const float* x    = (const float*)d_in[0];
    const float* mu   = (const float*)d_in[1];
    const float* prec = (const float*)d_in[2];
    float* out = (float*)d_out;

    unsigned short* Bf = (unsigned short*)d_ws;                 // 65536 B
    float* msq = (float*)((char*)d_ws + 65536);                 // +1024 B

    hipMemsetAsync(d_out, 0, sizeof(float), stream);
    prep_musq<<<1, 256, 0, stream>>>(mu, prec, msq);
    prep_frag<<<16, 256, 0, stream>>>(mu, prec, Bf);
    mixture_main<<<N_ROWS / 256, 256, 0, stream>>>(x, Bf, msq, prec, out);
}